// Round 1
// 251.750 us; speedup vs baseline: 1.3774x; 1.3774x over previous
//
#include <hip/hip_runtime.h>

// Backward (bilinear) warp: out[b,c,h,w] = bilinear_sample(input[b,c], w+flow_x, h+flow_y)
// Shapes: input [4,32,512,512] f32, flow [4,2,512,512] f32, out [4,32,512,512] f32.
//
// R3: latency-bound fix. R2's LDS-staged kernel (187us/dispatch) showed
// VALUBusy 8%, HBM 22% -> nothing saturated; 64 serial barrier phases with
// un-overlapped staging latency. This version:
//  - APRON 40->31: staged region = 128 rows x 128 dwords = 64 KiB exactly,
//    so TWO channel buffers fit in 128 KiB LDS (double-buffer).
//  - staging via __builtin_amdgcn_global_load_lds width=16: one wave instr
//    stages 2 rows (64 lanes x 16B = 1024B = 2*128 dwords), async, no VGPR
//    round-trip. Per-lane GLOBAL addr clamped for edge tiles; clamped cells
//    are never gathered (gather only touches |flow|<=31 region; outliers take
//    the rare global fallback).
//  - pipeline: issue stage(c+1) into buf^1, then gather(c) from buf, then ONE
//    __syncthreads per channel. The barrier's vmcnt drain lands after ~250
//    gather/store instructions -> staging latency hidden.

constexpr int B = 4, C = 32, H = 512, W = 512;
constexpr int HW = H * W;
constexpr int TILE = 64;
constexpr int APRON = 31;       // covers |flow| <= 31 (3.87 sigma of N(0,8))
constexpr int RH = 128;         // staged rows  (64 + 31 + 31 + 1, padded to 128)
constexpr int RW = 128;         // staged cols (dwords): 64 + 32 + 31 + 1 = 128
constexpr int BUF = RH * RW;    // 16384 dwords = 64 KiB per buffer

typedef __attribute__((address_space(1))) const unsigned int gas_u32;
typedef __attribute__((address_space(3))) unsigned int las_u32;

__global__ __launch_bounds__(1024, 4) void warp_tile_kernel(
    const float* __restrict__ input,
    const float* __restrict__ flow,
    float* __restrict__ out)
{
    __shared__ float s[2 * BUF];          // 128 KiB, double-buffered

    int bid = blockIdx.x;                 // 256 blocks = [b:4][ty:8][tx:8]
    int tx = bid & 7;
    int ty = (bid >> 3) & 7;
    int b  = bid >> 6;
    int tx0 = tx * TILE, ty0 = ty * TILE;

    // virtual region origin (may be negative; sources are clamped per-lane,
    // and clamped/garbage cells are provably never gathered)
    int rx0 = tx0 - 32;                   // 32 = APRON+1 keeps RW=128 & 16B align
    int ry0 = ty0 - APRON;

    int tid  = (int)threadIdx.x;
    int lane = tid & 63;
    int wv   = tid >> 6;                  // wave id 0..15
    int cl   = tid & 63;                  // output col within tile
    int rl   = tid >> 6;                  // output row group (rows rl+16p)

    // ---- staging source offsets (channel-relative dword offsets, per lane) ----
    // wave wv, issue i stages region rows r=8*wv+2*i and r+1:
    //   lanes 0..31 -> row r cols 4L..4L+3, lanes 32..63 -> row r+1.
    int soff[4];
    int sr[4];
    {
        int lrow = lane >> 5;                        // 0 or 1
        int lc   = (lane & 31) << 2;                 // 0..124
        int gcol = min(max(rx0 + lc, 0), W - 4);     // 16B-aligned, in-row
        #pragma unroll
        for (int i = 0; i < 4; ++i) {
            int r = 8 * wv + 2 * i;                  // wave-uniform
            sr[i] = r;
            int grow = min(max(ry0 + r + lrow, 0), H - 1);
            soff[i] = grow * W + gcol;
        }
    }

    // ---- per-pixel precompute (4 px/thread), reused across 32 channels ----
    float wa[4], wb_[4], wc_[4], wd_[4];
    int a0[4], a1[4];
    int opix0 = (ty0 + rl) * W + tx0 + cl;

    #pragma unroll
    for (int p = 0; p < 4; ++p) {
        int h = ty0 + rl + 16 * p;
        int w = tx0 + cl;
        int pix = h * W + w;
        float fx = flow[(b * 2 + 0) * HW + pix];
        float fy = flow[(b * 2 + 1) * HW + pix];
        float x = fminf(fmaxf((float)w + fx, 0.0f), (float)(W - 1));
        float y = fminf(fmaxf((float)h + fy, 0.0f), (float)(H - 1));
        float x0f = floorf(x), y0f = floorf(y);
        int x0 = (int)x0f, y0 = (int)y0f;
        int y1 = min(y0 + 1, H - 1);
        float dx = x - x0f, dy = y - y0f;
        // weights use UNCLAMPED x1f=x0f+1, y1f=y0f+1 (matches reference)
        wa[p]  = (1.f - dx) * (1.f - dy);
        wb_[p] = (1.f - dx) * dy;
        wc_[p] = dx * (1.f - dy);
        wd_[p] = dx * dy;
        int ax0 = x0 - rx0, ay0 = y0 - ry0, ay1 = y1 - ry0;
        // need ax0 in [0,126] (reads ax0+1), ay0>=0, ay1<=127
        bool inreg = (ax0 >= 0) && (ax0 <= RW - 2) && (ay0 >= 0) && (ay1 <= RH - 1);
        // at x0==x1 (image right edge) the +1 read hits a staged-garbage col,
        // but its weight wc==dx==0 -> harmless. Same for y at bottom edge.
        a0[p] = inreg ? (ay0 * RW + ax0) : -1;
        a1[p] = ay1 * RW + ax0;
    }

    const float* iplane = input + (size_t)b * C * HW;
    float* oplane = out + (size_t)b * C * HW;

    // async stage of channel c into buffer `buf` (4 wave-instrs, 8 rows/wave)
    auto stage = [&](int c, int buf) {
        const float* gc = iplane + (size_t)c * HW;
        #pragma unroll
        for (int i = 0; i < 4; ++i) {
            __builtin_amdgcn_global_load_lds(
                (gas_u32*)(gc + soff[i]),
                (las_u32*)(&s[buf * BUF + sr[i] * RW]),
                16, 0, 0);
        }
    };

    stage(0, 0);
    __syncthreads();   // drain prologue staging

    for (int c = 0; c < C; ++c) {
        if (c + 1 < C) stage(c + 1, (c + 1) & 1);   // async prefetch next channel

        int base = (c & 1) * BUF;
        float* oc = oplane + (size_t)c * HW;
        #pragma unroll
        for (int p = 0; p < 4; ++p) {
            float v;
            if (a0[p] >= 0) {
                int i0 = base + a0[p], i1 = base + a1[p];
                float v00 = s[i0], v01 = s[i0 + 1];
                float v10 = s[i1], v11 = s[i1 + 1];
                v = wa[p] * v00 + wc_[p] * v01 + wb_[p] * v10 + wd_[p] * v11;
            } else {
                // outlier (|flow|>APRON, P ~ 2e-4): recompute + global gather
                int h = ty0 + rl + 16 * p;
                int w = tx0 + cl;
                int pix = h * W + w;
                float fx = flow[(b * 2 + 0) * HW + pix];
                float fy = flow[(b * 2 + 1) * HW + pix];
                float x = fminf(fmaxf((float)w + fx, 0.0f), (float)(W - 1));
                float y = fminf(fmaxf((float)h + fy, 0.0f), (float)(H - 1));
                float x0f = floorf(x), y0f = floorf(y);
                int x0 = (int)x0f, y0 = (int)y0f;
                int x1 = min(x0 + 1, W - 1), y1 = min(y0 + 1, H - 1);
                float dx = x - x0f, dy = y - y0f;
                const float* pch = iplane + (size_t)c * HW;
                v = (1.f - dx) * (1.f - dy) * pch[y0 * W + x0]
                  + (1.f - dx) * dy         * pch[y1 * W + x0]
                  + dx * (1.f - dy)         * pch[y0 * W + x1]
                  + dx * dy                 * pch[y1 * W + x1];
            }
            oc[opix0 + 16 * p * W] = v;
        }
        // one barrier per channel: drains stage(c+1) vmcnt (latency already
        // covered by the gather above) + WAR protection for buf reuse
        __syncthreads();
    }
}

extern "C" void kernel_launch(void* const* d_in, const int* in_sizes, int n_in,
                              void* d_out, int out_size, void* d_ws, size_t ws_size,
                              hipStream_t stream) {
    const float* input = (const float*)d_in[0];
    const float* flow  = (const float*)d_in[1];
    float* out = (float*)d_out;

    int grid = B * (H / TILE) * (W / TILE);   // 256 blocks -> 1 per CU
    warp_tile_kernel<<<grid, 1024, 0, stream>>>(input, flow, out);
}